// Round 12
// baseline (4075.663 us; speedup 1.0000x reference)
//
#include <hip/hip_runtime.h>

// Shapes: VOCAB=128, EMBED=512, HIDDEN=1024, B=64, T=512. Inputs fp32, x int32.
// ws layout (bytes):
//   tableV : [128 vocab][4096 C] fp16   @ 0         (1 MB)  xin0+bias
//   fcwT   : [1024 k][128 v] fp16       @ 1048576   (256 KB)
//   bar    : [512 words] u32            @ 1310720   (2 KB)  class counters
//   hseq   : [514 buf][64 b][2048 k]f16 @ 1376256   (128.5 MB) fresh h per step
//   xin1r  : [16 slot][64 b][64 cg][64] f32 @ 136118272 (16 MB) xin1 ring
//
// R12 = R11 + DEADLOCK FIX: L1's last iteration (it=512) needs xin1(512)
// = W_ih1 · h1(buffer 512), produced by L0 iteration 512 — but R11's L0
// loop ran it<512 only, capping cnt0 at 8*512 while L1 polled 8*513 ->
// permanent spin. Fix: L0 runs it<=512 (one epilogue producer iteration).
// At it=512: poll 8*512 reachable; back-pressure 8*496 reachable; A from
// buffer 512 (valid); h1-store to buffer 513 (exists, unread, harmless);
// ring store slot 0 (last consumed by L1 at it=496, gated); arrival
// raises cnt0 to 8*513 releasing L1's final step.
//
// XIN1 OFFLOAD TO L0 (R11): L0 iter j already loads A = h1(j) (validated
// by its own top poll) — exactly the input xin1(j) = W_ih1·h1(j) needs.
// So L0 computes BOTH h1(j+1) (w_hh0 -> zs) and xin1(j) (w_ih1 -> zs2)
// from the same A regs: +32 MFMA/wave in L0's slack, second reduce, 8 KB
// fp32 store to a 16-deep ring. L1 becomes a K=1024 recurrence (w_hh1 on
// h2) + one v4f xin1 read per owner thread. Ring transport: agent-scope
// atomic store/load pair (R0-proven; ring slots are REUSED so fresh-buffer
// coherence does not apply — must write-through and bypass-read at L3).
// Back-pressure: L0 polls cnt1 >= 8*(it-16) before slot reuse (guard
// it>=17); deadlock-free (L0_j <- L1_{j-16} <- L0_{j-15}).
//
// Classes (256 blocks, 512 thr, 1 block/CU):
//   L0 (blk 0..127):  2m x 64 cg2 x 16 units; K=1024 (w_hh0 + w_ih1).
//     Poll cnt0 (own class, min-of-8) [+ cnt1 back-pressure]. it=0..512.
//   L1 (blk 128..255): 2m x 64 cg2 x 16 units; K=1024 (w_hh1 on h2).
//     Poll cnt0 >= 8*(it+1) (xin1(it) ready) + cnt1 >= 8*(it-1). it=1..512.
// Counters: cnt0[m][g] @ (m*8+g)*16, cnt1[m][g] @ ((2+m)*8+g)*16; arrival
// = tid0 atomicAdd after per-lane vmcnt(0) drain + sync (8 blocks/word).
//
// FRESH-BUFFER h EXCHANGE (R1): step it reads buffer it, writes buffer
// it+1; plain cached dwordx4 h loads are coherent (no XCD touched the
// buffer before its poll passed). h stores agent-scope relaxed atomics.
// Line-ownership: cg2 = xcd*8+idx; L0 writes k<1024, L1 writes k>=1024
// (disjoint 2-KB regions). buffer[t+2][b][1024+u] IS h2[t] -> FC direct.
//
// SWIZZLED LDS REDUCTION (R4/R10): zs[w8][r4][rq8][col64], col =
// (ct*16+colp)^((rq&1)<<4), colp=jj*4+g. Writes exactly 2 lanes/bank
// (free; measured 0 conflicts). Owner reads aligned v4f.
// Transcendentals: __expf + division only (proven on this harness).

typedef _Float16 v8h __attribute__((ext_vector_type(8)));
typedef float v4f __attribute__((ext_vector_type(4)));
typedef _Float16 h2v __attribute__((ext_vector_type(2)));
typedef unsigned long long u64t;

__device__ __forceinline__ float sigf(float x) {
  return 1.0f / (1.0f + __expf(-x));
}
__device__ __forceinline__ float tanhfast(float x) {
  // tanh = 1 - 2/(e^{2x}+1); graceful at +-inf (__expf -> inf/0)
  return 1.0f - 2.0f / (1.0f + __expf(2.0f * x));
}

// ---------------------------------------------------------------- prep ----
__global__ __launch_bounds__(256) void prep_kernel(
    const float* __restrict__ emb, const float* __restrict__ w_ih0,
    const float* __restrict__ b_ih0, const float* __restrict__ b_hh0,
    const float* __restrict__ fc_w, _Float16* __restrict__ tableV,
    _Float16* __restrict__ fcwT, unsigned* __restrict__ zbuf,
    unsigned* __restrict__ bar) {
  const int blk = blockIdx.x, tid = threadIdx.x;
  if (blk < 2048) {
    // tableV[v][C] = emb[v]·w_ih0[row(C)] + b_ih0[row] + b_hh0[row]
    const int C = blk * 2 + (tid >> 7);
    const int v = tid & 127;
    const int row =
        ((C >> 2) & 3) * 1024 + (C >> 5) * 8 + ((C >> 4) & 1) * 4 + (C & 3);
    const float* er = emb + v * 512;
    const float* wr = w_ih0 + row * 512;
    float a0 = 0.f, a1 = 0.f, a2 = 0.f, a3 = 0.f;
#pragma unroll 4
    for (int k = 0; k < 512; k += 4) {
      a0 = fmaf(er[k], wr[k], a0);
      a1 = fmaf(er[k + 1], wr[k + 1], a1);
      a2 = fmaf(er[k + 2], wr[k + 2], a2);
      a3 = fmaf(er[k + 3], wr[k + 3], a3);
    }
    tableV[v * 4096 + C] =
        (_Float16)(b_ih0[row] + b_hh0[row] + ((a0 + a1) + (a2 + a3)));
  } else if (blk < 2560) {
    const int idx = (blk - 2048) * 256 + tid;   // [0, 131072)
    const int v = idx & 127, k = idx >> 7;
    fcwT[k * 128 + v] = (_Float16)fc_w[v * 1024 + k];
  } else if (blk < 2592) {
    // zero hseq buffers 0 and 1 (step-0/1 initial h state): 131072 dwords
    const int idx = (blk - 2560) * 256 + tid;
#pragma unroll
    for (int q = 0; q < 16; ++q) zbuf[idx * 16 + q] = 0u;
  } else {
    for (int i = tid; i < 512; i += 256) bar[i] = 0u;
  }
}

// ------------------------------------------------------------ recurrent ----
__global__ __launch_bounds__(512, 1) void lstm_mfma(
    const int* __restrict__ x, const _Float16* __restrict__ tableV,
    const float* __restrict__ w_hh0, const float* __restrict__ w_ih1,
    const float* __restrict__ w_hh1, const float* __restrict__ b_ih1,
    const float* __restrict__ b_hh1, _Float16* __restrict__ hseq,
    float* __restrict__ xin1r, unsigned* __restrict__ bar) {
  // two reduce buffers: [w8][r4][rq8][col64] floats = 64 KB each (128 KB)
  __shared__ __align__(16) float zs[8 * 4 * 8 * 64];
  __shared__ __align__(16) float zs2[8 * 4 * 8 * 64];

  const int tid = threadIdx.x, blk = blockIdx.x;
  const bool isL1 = blk >= 128;
  const int sub = isL1 ? blk - 128 : blk;
  const int xcd = sub & 7, bidx = sub >> 3;        // xcd == blk&7 both classes
  const int m = bidx >> 3, cg2 = xcd * 8 + (bidx & 7);   // cg2 in 0..63
  const int w = tid >> 6, l = tid & 63;
  const int lane16 = l & 15, quad = l >> 4;
  const int g = lane16 >> 2, jj = lane16 & 3;
  const int colp = jj * 4 + g;                     // write col perm

  // --- owner constants (every thread owns one cell) ---
  const int b = w * 4 + quad;                      // batch row within m
  const int uu = lane16;                           // unit within block's 16
  const int bg = m * 32 + b;
  const int ubase = (isL1 ? 1024 : 0) + cg2 * 16;
  const int colo = ((uu >> 2) * 16 + (uu & 3) * 4) ^ ((w & 1) << 4);

  float cst = 0.0f;

  if (!isL1) {
    // ============ L0: critical recurrence + xin1 production ============
    // B-frags: w_hh0 (h1 recurrence) AND w_ih1 (xin1), k in [w*128,+128)
    v8h bfh[4][4], bfi[4][4];
#pragma unroll
    for (int ct = 0; ct < 4; ++ct) {
      const int row = g * 1024 + cg2 * 16 + ct * 4 + jj;
      const float* rph = w_hh0 + row * 1024 + w * 128 + quad * 8;
      const float* rpi = w_ih1 + row * 1024 + w * 128 + quad * 8;
#pragma unroll
      for (int kk = 0; kk < 4; ++kk) {
        const float4 h0 = *(const float4*)(rph + kk * 32);
        const float4 h1 = *(const float4*)(rph + kk * 32 + 4);
        const float4 i0 = *(const float4*)(rpi + kk * 32);
        const float4 i1 = *(const float4*)(rpi + kk * 32 + 4);
        v8h bh, bi;
        bh[0] = (_Float16)h0.x; bh[1] = (_Float16)h0.y;
        bh[2] = (_Float16)h0.z; bh[3] = (_Float16)h0.w;
        bh[4] = (_Float16)h1.x; bh[5] = (_Float16)h1.y;
        bh[6] = (_Float16)h1.z; bh[7] = (_Float16)h1.w;
        bi[0] = (_Float16)i0.x; bi[1] = (_Float16)i0.y;
        bi[2] = (_Float16)i0.z; bi[3] = (_Float16)i0.w;
        bi[4] = (_Float16)i1.x; bi[5] = (_Float16)i1.y;
        bi[6] = (_Float16)i1.z; bi[7] = (_Float16)i1.w;
        bfh[ct][kk] = bh;
        bfi[ct][kk] = bi;
      }
    }
    // xin0 gather constants
    const int Cbase = (cg2 * 2 + (uu >> 3)) * 32 + ((uu >> 2) & 1) * 16 + (uu & 3);
    _Float16 tvh[4];
    {
      const int xv = x[bg * 512];
#pragma unroll
      for (int gg = 0; gg < 4; ++gg)
        tvh[gg] = tableV[xv * 4096 + Cbase + gg * 4];
    }
    unsigned* arr = &bar[(m * 8 + xcd) * 16];
    const unsigned* pw0 = &bar[(m * 8) * 16];
    const unsigned* pw1 = &bar[((2 + m) * 8) * 16];

    // R12: it <= 512 — the it=512 epilogue iteration produces xin1(512)
    // (needed by L1's it=512) and raises cnt0 to 8*513. Its h1-store goes
    // to buffer 513 (unread) and its cell update is discarded — harmless.
    for (int it = 0; it <= 512; ++it) {
      if (tid == 0 && it > 0) {
        const unsigned tgt0 = 8u * (unsigned)it;
        const unsigned tgt1 = (it >= 17) ? 8u * (unsigned)(it - 16) : 0u;
        for (;;) {
          unsigned mn0 = 0xffffffffu, mn1 = 0xffffffffu;
#pragma unroll
          for (int gg = 0; gg < 8; ++gg) {
            const unsigned v0 = __hip_atomic_load(
                pw0 + gg * 16, __ATOMIC_RELAXED, __HIP_MEMORY_SCOPE_AGENT);
            const unsigned v1 = __hip_atomic_load(
                pw1 + gg * 16, __ATOMIC_RELAXED, __HIP_MEMORY_SCOPE_AGENT);
            mn0 = v0 < mn0 ? v0 : mn0;
            mn1 = v1 < mn1 ? v1 : mn1;
          }
          if (mn0 >= tgt0 && mn1 >= tgt1) break;
          __builtin_amdgcn_s_sleep(1);
        }
      }
      __syncthreads();
      asm volatile("" ::: "memory");
      const _Float16* hr = hseq + (size_t)it * 131072;
      _Float16* hw = hseq + (size_t)(it + 1) * 131072;

      // A = h1(it): rows m*32+lane16 (+16), k = w*128 + kk*32 + quad*8
      const _Float16* a0p = hr + (m * 32 + lane16) * 2048 + w * 128 + quad * 8;
      const _Float16* a1p = a0p + 16 * 2048;
      v8h A0[4], A1[4];
#pragma unroll
      for (int kk = 0; kk < 4; ++kk) A0[kk] = *(const v8h*)(a0p + kk * 32);
#pragma unroll
      for (int kk = 0; kk < 4; ++kk) A1[kk] = *(const v8h*)(a1p + kk * 32);
      v4f ac0[4] = {{0, 0, 0, 0}, {0, 0, 0, 0}, {0, 0, 0, 0}, {0, 0, 0, 0}};
      v4f ac1[4] = {{0, 0, 0, 0}, {0, 0, 0, 0}, {0, 0, 0, 0}, {0, 0, 0, 0}};
      v4f bc0[4] = {{0, 0, 0, 0}, {0, 0, 0, 0}, {0, 0, 0, 0}, {0, 0, 0, 0}};
      v4f bc1[4] = {{0, 0, 0, 0}, {0, 0, 0, 0}, {0, 0, 0, 0}, {0, 0, 0, 0}};
#pragma unroll
      for (int kk = 0; kk < 4; ++kk)
#pragma unroll
        for (int ct = 0; ct < 4; ++ct) {
          ac0[ct] = __builtin_amdgcn_mfma_f32_16x16x32_f16(A0[kk], bfh[ct][kk], ac0[ct], 0, 0, 0);
          ac1[ct] = __builtin_amdgcn_mfma_f32_16x16x32_f16(A1[kk], bfh[ct][kk], ac1[ct], 0, 0, 0);
          bc0[ct] = __builtin_amdgcn_mfma_f32_16x16x32_f16(A0[kk], bfi[ct][kk], bc0[ct], 0, 0, 0);
          bc1[ct] = __builtin_amdgcn_mfma_f32_16x16x32_f16(A1[kk], bfi[ct][kk], bc1[ct], 0, 0, 0);
        }

      // C-tiles -> LDS (swizzled; writes exactly 2 lanes/bank = free)
#pragma unroll
      for (int r = 0; r < 4; ++r)
#pragma unroll
        for (int ct = 0; ct < 4; ++ct) {
          const int col = (ct * 16 + colp) ^ ((quad & 1) << 4);
          zs[((w * 4 + r) * 8 + quad) * 64 + col] = ac0[ct][r];
          zs[((w * 4 + r) * 8 + 4 + quad) * 64 + col] = ac1[ct][r];
          zs2[((w * 4 + r) * 8 + quad) * 64 + col] = bc0[ct][r];
          zs2[((w * 4 + r) * 8 + 4 + quad) * 64 + col] = bc1[ct][r];
        }
      __syncthreads();

      // reduce1: h1 cell update
      v4f z;
      z[0] = (float)tvh[0]; z[1] = (float)tvh[1];
      z[2] = (float)tvh[2]; z[3] = (float)tvh[3];
#pragma unroll
      for (int wv = 0; wv < 8; ++wv)
        z += *(const v4f*)&zs[((wv * 4 + quad) * 8 + w) * 64 + colo];
      const float ig = sigf(z[0]), fg = sigf(z[1]);
      const float gg2 = tanhfast(z[2]), og = sigf(z[3]);
      cst = fg * cst + ig * gg2;
      const float hv = og * tanhfast(cst);

      const unsigned hu =
          (unsigned)__builtin_bit_cast(unsigned short, (_Float16)hv);
      const unsigned p1 = (unsigned)__shfl_xor((int)hu, 1, 64);
      const unsigned lo = (l & 1) ? ((p1 & 0xffffu) | (hu << 16))
                                  : ((hu & 0xffffu) | (p1 << 16));
      const unsigned p2 = (unsigned)__shfl_xor((int)lo, 2, 64);
      if ((l & 3) == 0) {
        const u64t val = (u64t)lo | ((u64t)p2 << 32);
        __hip_atomic_store((u64t*)(hw + bg * 2048 + ubase + (l & 15)), val,
                           __ATOMIC_RELAXED, __HIP_MEMORY_SCOPE_AGENT);
      }

      // reduce2: xin1(it) -> ring slot it&15 (agent-scope write-through)
      v4f z2 = {0.f, 0.f, 0.f, 0.f};
#pragma unroll
      for (int wv = 0; wv < 8; ++wv)
        z2 += *(const v4f*)&zs2[((wv * 4 + quad) * 8 + w) * 64 + colo];
      {
        u64t* xp = (u64t*)&xin1r[((((size_t)(it & 15) * 64 + bg) * 64 + cg2)
                                  << 6) + uu * 4];
        const ulonglong2 qq = __builtin_bit_cast(ulonglong2, z2);
        __hip_atomic_store(xp, qq.x, __ATOMIC_RELAXED,
                           __HIP_MEMORY_SCOPE_AGENT);
        __hip_atomic_store(xp + 1, qq.y, __ATOMIC_RELAXED,
                           __HIP_MEMORY_SCOPE_AGENT);
      }

      // prefetch next xin0 gather (tableV L2-hot)
      if (it + 1 < 512) {
        const int xv = x[bg * 512 + it + 1];
#pragma unroll
        for (int gg = 0; gg < 4; ++gg)
          tvh[gg] = tableV[xv * 4096 + Cbase + gg * 4];
      }
      asm volatile("s_waitcnt vmcnt(0)" ::: "memory");
      __syncthreads();
      if (tid == 0) atomicAdd(arr, 1u);
    }
  } else {
    // ============ L1: h2 recurrence (K=1024) + xin1 consumption ============
    // B-frags: w_hh1, k(within h2) in [w*128,+128)
    v8h bf[4][4];
#pragma unroll
    for (int ct = 0; ct < 4; ++ct) {
      const int row = g * 1024 + cg2 * 16 + ct * 4 + jj;
      const float* rp = w_hh1 + row * 1024 + w * 128 + quad * 8;
#pragma unroll
      for (int kk = 0; kk < 4; ++kk) {
        const float4 f0 = *(const float4*)(rp + kk * 32);
        const float4 f1 = *(const float4*)(rp + kk * 32 + 4);
        v8h bb;
        bb[0] = (_Float16)f0.x; bb[1] = (_Float16)f0.y;
        bb[2] = (_Float16)f0.z; bb[3] = (_Float16)f0.w;
        bb[4] = (_Float16)f1.x; bb[5] = (_Float16)f1.y;
        bb[6] = (_Float16)f1.z; bb[7] = (_Float16)f1.w;
        bf[ct][kk] = bb;
      }
    }
    v4f bias4;
#pragma unroll
    for (int gg = 0; gg < 4; ++gg) {
      const int row = gg * 1024 + cg2 * 16 + uu;
      bias4[gg] = b_ih1[row] + b_hh1[row];
    }
    unsigned* arr = &bar[((2 + m) * 8 + xcd) * 16];
    const unsigned* pw0 = &bar[(m * 8) * 16];
    const unsigned* pw1 = &bar[((2 + m) * 8) * 16];

    for (int it = 1; it <= 512; ++it) {
      if (tid == 0) {
        const unsigned t0 = 8u * (unsigned)(it + 1);   // xin1(it) ready
        const unsigned t1 = 8u * (unsigned)(it - 1);   // h2(it) ready
        for (;;) {
          unsigned mn0 = 0xffffffffu, mn1 = 0xffffffffu;
#pragma unroll
          for (int gg = 0; gg < 8; ++gg) {
            const unsigned v0 = __hip_atomic_load(
                pw0 + gg * 16, __ATOMIC_RELAXED, __HIP_MEMORY_SCOPE_AGENT);
            const unsigned v1 = __hip_atomic_load(
                pw1 + gg * 16, __ATOMIC_RELAXED, __HIP_MEMORY_SCOPE_AGENT);
            mn0 = v0 < mn0 ? v0 : mn0;
            mn1 = v1 < mn1 ? v1 : mn1;
          }
          if (mn0 >= t0 && mn1 >= t1) break;
          __builtin_amdgcn_s_sleep(1);
        }
      }
      __syncthreads();
      asm volatile("" ::: "memory");
      const _Float16* hr = hseq + (size_t)it * 131072;
      _Float16* hw = hseq + (size_t)(it + 1) * 131072;

      // xin1 prefetch (ring slot reused -> MUST bypass L2: atomic loads)
      const u64t* xp = (const u64t*)&xin1r[((((size_t)(it & 15) * 64 + bg) *
                                            64 + cg2) << 6) + uu * 4];
      const u64t xlo = __hip_atomic_load(xp, __ATOMIC_RELAXED,
                                         __HIP_MEMORY_SCOPE_AGENT);
      const u64t xhi = __hip_atomic_load(xp + 1, __ATOMIC_RELAXED,
                                         __HIP_MEMORY_SCOPE_AGENT);

      // A = h2(it): rows m*32+lane16 (+16), k = 1024 + w*128 + kk*32 + quad*8
      const _Float16* a0p =
          hr + (m * 32 + lane16) * 2048 + 1024 + w * 128 + quad * 8;
      const _Float16* a1p = a0p + 16 * 2048;
      v8h A0[4], A1[4];
#pragma unroll
      for (int kk = 0; kk < 4; ++kk) A0[kk] = *(const v8h*)(a0p + kk * 32);
#pragma unroll
      for (int kk = 0; kk < 4; ++kk) A1[kk] = *(const v8h*)(a1p + kk * 32);
      v4f ac0[4] = {{0, 0, 0, 0}, {0, 0, 0, 0}, {0, 0, 0, 0}, {0, 0, 0, 0}};
      v4f ac1[4] = {{0, 0, 0, 0}, {0, 0, 0, 0}, {0, 0, 0, 0}, {0, 0, 0, 0}};
#pragma unroll
      for (int kk = 0; kk < 4; ++kk)
#pragma unroll
        for (int ct = 0; ct < 4; ++ct) {
          ac0[ct] = __builtin_amdgcn_mfma_f32_16x16x32_f16(A0[kk], bf[ct][kk], ac0[ct], 0, 0, 0);
          ac1[ct] = __builtin_amdgcn_mfma_f32_16x16x32_f16(A1[kk], bf[ct][kk], ac1[ct], 0, 0, 0);
        }

#pragma unroll
      for (int r = 0; r < 4; ++r)
#pragma unroll
        for (int ct = 0; ct < 4; ++ct) {
          const int col = (ct * 16 + colp) ^ ((quad & 1) << 4);
          zs[((w * 4 + r) * 8 + quad) * 64 + col] = ac0[ct][r];
          zs[((w * 4 + r) * 8 + 4 + quad) * 64 + col] = ac1[ct][r];
        }
      __syncthreads();

      ulonglong2 xq;
      xq.x = xlo;
      xq.y = xhi;
      v4f z = bias4 + __builtin_bit_cast(v4f, xq);
#pragma unroll
      for (int wv = 0; wv < 8; ++wv)
        z += *(const v4f*)&zs[((wv * 4 + quad) * 8 + w) * 64 + colo];
      const float ig = sigf(z[0]), fg = sigf(z[1]);
      const float gg2 = tanhfast(z[2]), og = sigf(z[3]);
      cst = fg * cst + ig * gg2;
      const float hv = og * tanhfast(cst);

      const unsigned hu =
          (unsigned)__builtin_bit_cast(unsigned short, (_Float16)hv);
      const unsigned p1 = (unsigned)__shfl_xor((int)hu, 1, 64);
      const unsigned lo = (l & 1) ? ((p1 & 0xffffu) | (hu << 16))
                                  : ((hu & 0xffffu) | (p1 << 16));
      const unsigned p2 = (unsigned)__shfl_xor((int)lo, 2, 64);
      if ((l & 3) == 0) {
        const u64t val = (u64t)lo | ((u64t)p2 << 32);
        __hip_atomic_store((u64t*)(hw + bg * 2048 + ubase + (l & 15)), val,
                           __ATOMIC_RELAXED, __HIP_MEMORY_SCOPE_AGENT);
      }
      asm volatile("s_waitcnt vmcnt(0)" ::: "memory");
      __syncthreads();
      if (tid == 0) atomicAdd(arr, 1u);
    }
  }
}

// ---------------------------------------------------------------- FC ----
__global__ __launch_bounds__(256, 2) void fc_kernel(
    const _Float16* __restrict__ hseq, const _Float16* __restrict__ fcwT,
    const float* __restrict__ fc_b, float* __restrict__ out) {
  __shared__ float hl[16][1024];      // 64 KB
  const int tid = threadIdx.x;
  const int t = blockIdx.x >> 2, bs = blockIdx.x & 3;
  const int v = tid & 127, hh = tid >> 7;

  // h2[t][b][u] lives at hseq buffer t+2, row b, halfs 1024..2047
  const h2v* hp = (const h2v*)hseq;
  const size_t base = (size_t)(t + 2) * 65536 + 512;
  for (int idx = tid; idx < 8192; idx += 256) {
    const int bl = idx >> 9, kp = idx & 511;
    const h2v pr = hp[base + (size_t)((bs * 16 + bl)) * 1024 + kp];
    hl[bl][2 * kp] = (float)pr.x;
    hl[bl][2 * kp + 1] = (float)pr.y;
  }
  __syncthreads();

  float acc[8];
#pragma unroll
  for (int i = 0; i < 8; ++i) acc[i] = 0.0f;
  const int bl0 = hh * 8;
#pragma unroll 1
  for (int k4 = 0; k4 < 256; ++k4) {
    const int k = k4 * 4;
    const float w0 = (float)fcwT[(k + 0) * 128 + v];
    const float w1 = (float)fcwT[(k + 1) * 128 + v];
    const float w2 = (float)fcwT[(k + 2) * 128 + v];
    const float w3 = (float)fcwT[(k + 3) * 128 + v];
#pragma unroll
    for (int i = 0; i < 8; ++i) {
      const float4 hv = *(const float4*)&hl[bl0 + i][k];
      acc[i] += hv.x * w0 + hv.y * w1 + hv.z * w2 + hv.w * w3;
    }
  }
  const float bias = fc_b[v];
#pragma unroll
  for (int i = 0; i < 8; ++i) {
    const int bb = bs * 16 + bl0 + i;
    out[(bb * 512 + t) * 128 + v] = acc[i] + bias;
  }
}

// ------------------------------------------------------------- launch ----
extern "C" void kernel_launch(void* const* d_in, const int* in_sizes, int n_in,
                              void* d_out, int out_size, void* d_ws,
                              size_t ws_size, hipStream_t stream) {
  const int* x = (const int*)d_in[0];
  const float* emb = (const float*)d_in[1];
  const float* w_ih0 = (const float*)d_in[2];
  const float* w_hh0 = (const float*)d_in[3];
  const float* b_ih0 = (const float*)d_in[4];
  const float* b_hh0 = (const float*)d_in[5];
  const float* w_ih1 = (const float*)d_in[6];
  const float* w_hh1 = (const float*)d_in[7];
  const float* b_ih1 = (const float*)d_in[8];
  const float* b_hh1 = (const float*)d_in[9];
  const float* fc_w = (const float*)d_in[10];
  const float* fc_b = (const float*)d_in[11];
  float* out = (float*)d_out;

  char* ws = (char*)d_ws;
  _Float16* tableV = (_Float16*)(ws);
  _Float16* fcwT = (_Float16*)(ws + 1048576);
  unsigned* bar = (unsigned*)(ws + 1310720);
  _Float16* hseq = (_Float16*)(ws + 1376256);       // 514 x 262144 B
  float* xin1r = (float*)(ws + 136118272);          // 16 x 1 MB ring
  unsigned* zb = (unsigned*)(ws + 1376256);         // zero buffers 0,1

  prep_kernel<<<2593, 256, 0, stream>>>(emb, w_ih0, b_ih0, b_hh0, fc_w,
                                        tableV, fcwT, zb, bar);

  const _Float16* tableVc = tableV;
  _Float16* hseqa = hseq;
  float* xin1ra = xin1r;
  unsigned* bara = bar;
  void* args[] = {(void*)&x,     (void*)&tableVc, (void*)&w_hh0,
                  (void*)&w_ih1, (void*)&w_hh1,   (void*)&b_ih1,
                  (void*)&b_hh1, (void*)&hseqa,   (void*)&xin1ra,
                  (void*)&bara};
  hipLaunchCooperativeKernel(lstm_mfma, dim3(256), dim3(512), args, 0, stream);

  fc_kernel<<<2048, 256, 0, stream>>>(hseq, fcwT, fc_b, out);
}